// Round 1
// baseline (233.932 us; speedup 1.0000x reference)
//
#include <hip/hip_runtime.h>

// Problem constants (from setup_inputs): B=8, N=2048, D=128.
#define BSZ   8
#define NN    2048
#define DD    128
#define NROWS (BSZ * NN)          // 16384
#define N4    (NN / 4)            // 512 float4 per row
#define P_A   0.8f
#define P_B   0.2f

// Kernel 1: per-row dot products.
// si[row] = dot(x[row], W[0:128]) + bias ; sj[row] = dot(x[row], W[128:256])
// One 64-lane wave per row; each lane handles 2 of the 128 elements.
__global__ __launch_bounds__(256) void row_dots(const float* __restrict__ x,
                                                const float* __restrict__ W,
                                                const float* __restrict__ bias,
                                                float* __restrict__ si,
                                                float* __restrict__ sj) {
    int gtid = blockIdx.x * blockDim.x + threadIdx.x;
    int row  = gtid >> 6;         // wave index = row
    int lane = threadIdx.x & 63;
    if (row >= NROWS) return;

    const float* xr = x + (size_t)row * DD;
    float x0 = xr[lane];
    float x1 = xr[lane + 64];

    float a = x0 * W[lane]       + x1 * W[lane + 64];    // si part
    float c = x0 * W[lane + 128] + x1 * W[lane + 192];   // sj part

    // 64-lane butterfly reduction
    #pragma unroll
    for (int off = 32; off > 0; off >>= 1) {
        a += __shfl_down(a, off, 64);
        c += __shfl_down(c, off, 64);
    }
    if (lane == 0) {
        si[row] = a + bias[0];
        sj[row] = c;
    }
}

// Kernel 2: streaming fuse. One thread per float4 of the [B,N,N] output.
__global__ __launch_bounds__(256) void fuse_kernel(const float4* __restrict__ adj,
                                                   const float*  __restrict__ si,
                                                   const float4* __restrict__ sj,
                                                   float4* __restrict__ out) {
    int idx = blockIdx.x * blockDim.x + threadIdx.x;   // [0, B*N*N/4)
    // idx layout: row-major over (b, i, j4)
    int j4  = idx & (N4 - 1);       // j quad within row
    int row = idx >> 9;             // b*N + i   (N4 = 512 = 2^9)
    int b   = row >> 11;            // N = 2048 = 2^11

    float  s   = si[row];                       // wave-uniform-ish broadcast
    float4 sv  = sj[(b << 9) + j4];             // coalesced across lanes
    float4 av  = adj[idx];                      // coalesced stream

    float t0 = s + sv.x;
    float t1 = s + sv.y;
    float t2 = s + sv.z;
    float t3 = s + sv.w;

    float4 o;
    o.x = P_A * (1.0f / (1.0f + __expf(-t0))) + P_B * av.x;
    o.y = P_A * (1.0f / (1.0f + __expf(-t1))) + P_B * av.y;
    o.z = P_A * (1.0f / (1.0f + __expf(-t2))) + P_B * av.z;
    o.w = P_A * (1.0f / (1.0f + __expf(-t3))) + P_B * av.w;

    out[idx] = o;
}

extern "C" void kernel_launch(void* const* d_in, const int* in_sizes, int n_in,
                              void* d_out, int out_size, void* d_ws, size_t ws_size,
                              hipStream_t stream) {
    const float* x    = (const float*)d_in[0];   // [B,N,D]
    const float* adj  = (const float*)d_in[1];   // [B,N,N]
    const float* W    = (const float*)d_in[2];   // [2D]
    const float* bias = (const float*)d_in[3];   // scalar

    float* si = (float*)d_ws;            // NROWS floats
    float* sj = si + NROWS;              // NROWS floats  (total 128 KiB)

    // Kernel 1: 16384 rows, 4 waves (256 threads) per block -> 4096 blocks
    row_dots<<<NROWS / 4, 256, 0, stream>>>(x, W, bias, si, sj);

    // Kernel 2: B*N*N/4 float4 threads
    const int total4 = BSZ * NN * NN / 4;        // 8,388,608
    fuse_kernel<<<total4 / 256, 256, 0, stream>>>(
        (const float4*)adj, si, (const float4*)sj, (float4*)d_out);
}